// Round 3
// baseline (415.804 us; speedup 1.0000x reference)
//
#include <hip/hip_runtime.h>
#include <hip/hip_bf16.h>
#include <math.h>

// Problem constants (fixed by the reference file)
#define N     8192
#define F_IN  256
#define F_OUT 64
#define ALPHA 0.2f

// ---------------------------------------------------------------------------
// Kernel B: Wh = h @ W   [N, 64]; wh1[u] = Wh[u,:]@a[64:128]; wh2[u] = Wh[u,:]@a[0:64]
// 8 rows per wave / 32 rows per block: each coalesced W load is reused 8x.
// Grid: 256 blocks x 256 threads.
// ---------------------------------------------------------------------------
__global__ __launch_bounds__(256) void gat_wh_kernel(
    const float* __restrict__ h,      // [N, 256]
    const float* __restrict__ W,      // [256, 64]
    const float* __restrict__ a,      // [128]
    float* __restrict__ Wh,           // [N, 64]
    float* __restrict__ wh1,          // [N]
    float* __restrict__ wh2,          // [N]
    float* __restrict__ colpart)      // [256, 64]
{
    __shared__ float s_h[32][F_IN];   // 32 rows of h (32 KiB)
    __shared__ float s_cp[256];

    const int tid = threadIdx.x;
    const int wv  = tid >> 6;         // wave id 0..3
    const int ln  = tid & 63;         // lane -> output feature
    const int rowbase = blockIdx.x * 32;

    // Stage 32 h rows (2048 float4, coalesced: 8 per thread)
    const float4* hsrc = (const float4*)(h + (size_t)rowbase * F_IN);
    float4* hdst = (float4*)&s_h[0][0];
#pragma unroll
    for (int i = 0; i < 8; ++i) hdst[tid + 256 * i] = hsrc[tid + 256 * i];
    __syncthreads();

    const int r0 = wv * 8;            // this wave's first row (within block)
    float acc[8] = {0.f, 0.f, 0.f, 0.f, 0.f, 0.f, 0.f, 0.f};

    // k-loop: one coalesced W load (float per lane), 8 LDS broadcasts + 8 fma
#pragma unroll 4
    for (int k2 = 0; k2 < F_IN / 2; ++k2) {
        const int k = k2 * 2;
        const float wk0 = W[(k + 0) * F_OUT + ln];
        const float wk1 = W[(k + 1) * F_OUT + ln];
#pragma unroll
        for (int r = 0; r < 8; ++r) {
            const float2 hv = *(const float2*)&s_h[r0 + r][k];  // LDS broadcast
            acc[r] += hv.x * wk0 + hv.y * wk1;
        }
    }

    const float a2 = a[ln];           // dest term coeff
    const float a1 = a[F_OUT + ln];   // source term coeff
    float colacc = 0.f;

#pragma unroll
    for (int r = 0; r < 8; ++r) {
        const int u = rowbase + r0 + r;
        Wh[(size_t)u * F_OUT + ln] = acc[r];     // coalesced 256B store
        colacc += acc[r];
        float p1 = acc[r] * a1;
        float p2 = acc[r] * a2;
#pragma unroll
        for (int off = 32; off > 0; off >>= 1) {
            p1 += __shfl_down(p1, off);
            p2 += __shfl_down(p2, off);
        }
        if (ln == 0) { wh1[u] = p1; wh2[u] = p2; }
    }

    // Per-block column-sum partial of Wh
    s_cp[tid] = colacc;
    __syncthreads();
    if (tid < 64) {
        colpart[(size_t)blockIdx.x * 64 + tid] =
            s_cp[tid] + s_cp[tid + 64] + s_cp[tid + 128] + s_cp[tid + 192];
    }
}

// ---------------------------------------------------------------------------
// Kernel C: colsum[f] = sum_b colpart[b][f].  Grid: 1 block x 256 threads.
// ---------------------------------------------------------------------------
__global__ __launch_bounds__(256) void gat_colsum_kernel(
    const float* __restrict__ colpart,   // [256, 64]
    float* __restrict__ colsum)          // [64]
{
    __shared__ float r[256];
    const int tid = threadIdx.x;
    const int f = tid & 63;
    const int g = tid >> 6;
    float s = 0.f;
    for (int b = g; b < 256; b += 4) s += colpart[(size_t)b * 64 + f];
    r[tid] = s;
    __syncthreads();
    if (tid < 64) {
        colsum[f] = r[f] + r[f + 64] + r[f + 128] + r[f + 192];
    }
}

// ---------------------------------------------------------------------------
// Kernel D: one WAVE per row, lane = output feature.
//   out[u,f] = elu( (sum_edges w_i * Wh[i,f] + colsum[f]) / (sum_edges w_i + N) )
// with w_i = expm1(leakyrelu(wh1[u] + wh2[i])).
// v3: software-pipelined adj stream (prefetch next 1024-col chunk during the
// walk) + per-lane precomputed edge weights shared via __shfl (no per-edge
// L2 load / expm1 on the critical path). No LDS, no barriers, no atomics.
// ---------------------------------------------------------------------------
__global__ __launch_bounds__(256) void gat_main_kernel(
    const float* __restrict__ adj,     // [N, N]
    const float* __restrict__ Wh,      // [N, 64]
    const float* __restrict__ wh1,     // [N]
    const float* __restrict__ wh2,     // [N]
    const float* __restrict__ colsum,  // [64]
    float* __restrict__ out)           // [N, 64]
{
    const int tid  = threadIdx.x;
    const int lane = tid & 63;         // feature index
    const int wv   = tid >> 6;
    const int u    = blockIdx.x * 4 + wv;   // row handled by this wave

    const float wh1u = wh1[u];
    const float* __restrict__ arow = adj + (size_t)u * N;

    float acc  = 0.f;                  // accumulator for feature `lane`
    float sumw = 0.f;                  // uniform across lanes

    // 8 chunks of 1024 cols; lane owns 16 consecutive floats per chunk.
    const float4* p0 = (const float4*)arow + lane * 4;
    float4 b0 = p0[0], b1 = p0[1], b2 = p0[2], b3 = p0[3];

    for (int it = 0; it < 8; ++it) {
        const float4 v0 = b0, v1 = b1, v2 = b2, v3 = b3;
        if (it < 7) {  // prefetch next chunk while walking this one
            const float4* np = (const float4*)(arow + (it + 1) * 1024) + lane * 4;
            b0 = np[0]; b1 = np[1]; b2 = np[2]; b3 = np[3];
        }
        const int cbase = it * 1024;
        const float vals[16] = {v0.x, v0.y, v0.z, v0.w, v1.x, v1.y, v1.z, v1.w,
                                v2.x, v2.y, v2.z, v2.w, v3.x, v3.y, v3.z, v3.w};
#pragma unroll
        for (int j = 0; j < 16; ++j) {
            const bool nz = (vals[j] != 0.f);
            float w_own = 0.f;
            if (nz) {   // predicated; skipped by execz when no lane has an edge
                float e = wh1u + wh2[cbase + lane * 16 + j];
                e = (e >= 0.f) ? e : ALPHA * e;   // LeakyReLU
                w_own = expm1f(e);                // exp(e) - 1
            }
            unsigned long long m = __ballot(nz);
            while (m) {                            // wave-uniform mask walk
                const int l = __ffsll((long long)m) - 1;
                m &= m - 1;
                const float w = __shfl(w_own, l);  // register broadcast
                const int col = cbase + (l << 4) + j;
                sumw += w;
                acc += w * Wh[((size_t)col << 6) + lane];  // coalesced 256B row
            }
        }
    }

    // Per-lane epilogue — no reductions needed.
    const float val = (acc + colsum[lane]) / (sumw + (float)N);
    out[((size_t)u << 6) + lane] = (val > 0.f) ? val : expm1f(val);
}

// ---------------------------------------------------------------------------
// Launch
// ---------------------------------------------------------------------------
extern "C" void kernel_launch(void* const* d_in, const int* in_sizes, int n_in,
                              void* d_out, int out_size, void* d_ws, size_t ws_size,
                              hipStream_t stream) {
    const float* h   = (const float*)d_in[0];   // [8192, 256]
    const float* adj = (const float*)d_in[1];   // [8192, 8192]
    const float* W   = (const float*)d_in[2];   // [256, 64]
    const float* a   = (const float*)d_in[3];   // [128, 1]
    float* out = (float*)d_out;                 // [8192, 64]

    // Workspace layout (floats)
    float* ws      = (float*)d_ws;
    float* Wh      = ws;                        // 524288
    float* wh1     = Wh + (size_t)N * F_OUT;    // 8192
    float* wh2     = wh1 + N;                   // 8192
    float* colpart = wh2 + N;                   // 256*64 = 16384
    float* colsum  = colpart + 256 * 64;        // 64

    gat_wh_kernel<<<N / 32, 256, 0, stream>>>(h, W, a, Wh, wh1, wh2, colpart);
    gat_colsum_kernel<<<1, 256, 0, stream>>>(colpart, colsum);
    gat_main_kernel<<<N / 4, 256, 0, stream>>>(adj, Wh, wh1, wh2, colsum, out);
}